// Round 2
// baseline (488.454 us; speedup 1.0000x reference)
//
#include <hip/hip_runtime.h>
#include <stdint.h>

// Problem constants (B=2, R=190 -> 380 pairs)
#define PAIRS  380
#define CDIM   512
#define EDIM   256
#define HDIM   8
#define DDIM   32
#define CHUNK  64
#define NSPLIT 8           // phase-1 blocks per pair (1 chunk each)

// ---- per-pair scratch layout (float offsets) ----
#define Q_OFF      0       // [512][8]   raw q (elu+1)
#define MSH_OFF    4096    // [8][256]   Msh
#define YP_OFF     6144    // [NSPLIT][8][256] y partials
#define QS_OFF     22528   // [NSPLIT][8] Qsum partials
#define KS_OFF     22592   // [NSPLIT][8] Ksum partials
#define SCR_FLOATS 22656
#define OUT_STRIDE 131072  // floats per pair in the output buffer

// ---- workspace byte offsets (before per-pair scratch) ----
#define WS_CW_OFF   1024   // canonical Wq(8)+Wk(8) rows, fp32 [16][256]
#define WS_CB_OFF   17408  // canonical bq(8)+bk(8) fp32 [16]
#define WS_SCR_OFF  32768

__device__ __forceinline__ float bf2f(uint16_t u) {
  union { uint32_t i; float f; } v; v.i = ((uint32_t)u) << 16; return v.f;
}
__device__ __forceinline__ uint16_t f2bf(float f) {
  union { float f; uint32_t i; } v; v.f = f;
  return (uint16_t)((v.i + 0x7FFFu + ((v.i >> 16) & 1u)) >> 16);  // RNE
}
__device__ __forceinline__ float blo(uint32_t u) {
  union { uint32_t i; float f; } v; v.i = u << 16; return v.f;
}
__device__ __forceinline__ float bhi(uint32_t u) {
  union { uint32_t i; float f; } v; v.i = u & 0xFFFF0000u; return v.f;
}

// Dtype-generic loads; f32 flag is wave-uniform (runtime). idx%4==0 for ld4.
__device__ __forceinline__ float4 ld4(const void* p, size_t idx, int f32) {
  if (f32) return ((const float4*)p)[idx >> 2];
  ushort4 u = *(const ushort4*)((const uint16_t*)p + idx);
  return make_float4(bf2f(u.x), bf2f(u.y), bf2f(u.z), bf2f(u.w));
}
__device__ __forceinline__ float ld1(const void* p, size_t idx, int f32) {
  return f32 ? ((const float*)p)[idx] : bf2f(((const uint16_t*)p)[idx]);
}

// Per-input dtype sniff (1 => fp32; all-zero -> bf16, safe either way) +
// canonical fp32 pack of Wq/Wk/bq/bk so phase1's hot loop is flag-free.
__global__ void sniff_pack(const uint16_t* p0, const uint16_t* p1, const uint16_t* p2,
                           const uint16_t* p3, const uint16_t* p4, const uint16_t* p5,
                           const uint16_t* p6, const uint16_t* p7, const uint16_t* p8,
                           int n0, int n1, int n2, int n3, int n4, int n5, int n6,
                           int n7, int n8, int* __restrict__ flags,
                           float* __restrict__ cw, float* __restrict__ cb) {
  const uint16_t* ps[9] = {p0, p1, p2, p3, p4, p5, p6, p7, p8};
  const int       ns[9] = {n0, n1, n2, n3, n4, n5, n6, n7, n8};
  __shared__ int sf;
  __shared__ int sflags[9];
  const int tid = threadIdx.x;
  #pragma unroll
  for (int j = 0; j < 9; ++j) {
    if (tid == 0) sf = 0;
    __syncthreads();
    const uint16_t* p = ps[j];
    int lim = ns[j] < 4096 ? ns[j] : 4096;
    int huge = 0;
    for (int i = tid; i < lim; i += 256) {
      int e = (p[i] >> 7) & 0xFF;
      huge |= (e >= 0xA0);
    }
    if (huge) atomicOr(&sf, 1);
    __syncthreads();
    if (tid == 0) { flags[j] = sf; sflags[j] = sf; }
    __syncthreads();
  }
  // canonical pack (rows 0..7 = Wq, 8..15 = Wk)
  for (int i = tid; i < 16 * EDIM; i += 256) {
    int r = i >> 8, c = i & 255;
    cw[i] = (r < 8) ? ld1(p1, (size_t)r * EDIM + c, sflags[1])
                    : ld1(p3, (size_t)(r - 8) * EDIM + c, sflags[3]);
  }
  if (tid < 8)       cb[tid] = ld1(p2, tid, sflags[2]);
  else if (tid < 16) cb[tid] = ld1(p4, tid - 8, sflags[4]);
}

// ---- Phase 1: one (pair, chunk) per block. 3040 blocks, 4 blocks/CU.
// xs: unpadded [64][256] bf16 with 16B-segment XOR swizzle (seg ^= row&7) ->
// conflict-free b128 row reads. Weights read from global (canonical fp32,
// group-uniform addresses, L1-hot) -- no weight LDS traffic at all.
__global__ void __launch_bounds__(256, 4)
sla_phase1(const void* __restrict__ xg,
           const float* __restrict__ cw, const float* __restrict__ cb,
           const int* __restrict__ flags,
           float* __restrict__ scratch, long long sstride)
{
  const int fx = flags[0];
  __shared__ __align__(16) uint16_t xs[CHUNK][256];   // 32768 B (swizzled segs)
  __shared__ __align__(16) float    kc[CHUNK][HDIM];  //  2048 B

  const int tid   = threadIdx.x;
  const int pair  = blockIdx.x >> 3;
  const int sp    = blockIdx.x & 7;
  const int cbase = sp * CHUNK;
  const size_t xelem = ((size_t)pair * CDIM + cbase) * EDIM;
  float* sbase = scratch + (size_t)pair * (size_t)sstride;
  char*  xb    = (char*)&xs[0][0];

  // ---- stage 64x256 chunk into LDS as bf16 (seg-XOR swizzle) ----
  if (!fx) {
    const uint4* xp = (const uint4*)xg + (xelem >> 3);
    #pragma unroll
    for (int i = 0; i < 8; ++i) {
      int u = i * 256 + tid;
      int c = u >> 5, s = u & 31;
      uint4 v = xp[u];
      *(uint4*)(xb + c * 512 + ((s ^ (c & 7)) << 4)) = v;
    }
  } else {
    const float4* xp = (const float4*)xg + (xelem >> 2);
    #pragma unroll
    for (int i = 0; i < 16; ++i) {
      int u = i * 256 + tid;
      int c = u >> 6, q4 = u & 63;
      float4 xv = xp[u];
      ushort4 sv; sv.x = f2bf(xv.x); sv.y = f2bf(xv.y); sv.z = f2bf(xv.z); sv.w = f2bf(xv.w);
      int s = q4 >> 1, half = q4 & 1;
      *(ushort4*)(xb + c * 512 + ((s ^ (c & 7)) << 4) + (half << 3)) = sv;
    }
  }
  __syncthreads();

  // ---- projection: 8 groups x 32 lanes; each thread 2 rows x 2 heads ----
  const int g  = tid >> 5;                       // 0..3 q-pairs, 4..7 k-pairs
  const int l  = tid & 31;                       // rows l, l+32
  const int wr = (g < 4) ? (g << 1) : (8 + ((g - 4) << 1));
  const int h0 = (g & 3) << 1;
  const float* w0 = cw + (size_t)wr * EDIM;
  const float* w1 = w0 + EDIM;
  float a00 = cb[wr], a01 = cb[wr + 1];          // row l
  float a10 = cb[wr], a11 = cb[wr + 1];          // row l+32
  const char* xr0 = xb + l * 512;
  const char* xr1 = xr0 + 32 * 512;
  const int   sw  = l & 7;                       // (l+32)&7 == l&7

  #pragma unroll 8
  for (int s = 0; s < 32; ++s) {
    uint4 xl = *(const uint4*)(xr0 + ((s ^ sw) << 4));
    uint4 xh = *(const uint4*)(xr1 + ((s ^ sw) << 4));
    float4 wa = *(const float4*)(w0 + s * 8);
    float4 wb = *(const float4*)(w0 + s * 8 + 4);
    float4 wc = *(const float4*)(w1 + s * 8);
    float4 wd = *(const float4*)(w1 + s * 8 + 4);
    float x0 = blo(xl.x), x1 = bhi(xl.x), x2 = blo(xl.y), x3 = bhi(xl.y);
    float x4 = blo(xl.z), x5 = bhi(xl.z), x6 = blo(xl.w), x7 = bhi(xl.w);
    a00 += x0*wa.x + x1*wa.y + x2*wa.z + x3*wa.w + x4*wb.x + x5*wb.y + x6*wb.z + x7*wb.w;
    a01 += x0*wc.x + x1*wc.y + x2*wc.z + x3*wc.w + x4*wd.x + x5*wd.y + x6*wd.z + x7*wd.w;
    float y0 = blo(xh.x), y1 = bhi(xh.x), y2 = blo(xh.y), y3 = bhi(xh.y);
    float y4 = blo(xh.z), y5 = bhi(xh.z), y6 = blo(xh.w), y7 = bhi(xh.w);
    a10 += y0*wa.x + y1*wa.y + y2*wa.z + y3*wa.w + y4*wb.x + y5*wb.y + y6*wb.z + y7*wb.w;
    a11 += y0*wc.x + y1*wc.y + y2*wc.z + y3*wc.w + y4*wd.x + y5*wd.y + y6*wd.z + y7*wd.w;
  }
  a00 = (a00 > 0.f) ? a00 + 1.f : __expf(a00);
  a01 = (a01 > 0.f) ? a01 + 1.f : __expf(a01);
  a10 = (a10 > 0.f) ? a10 + 1.f : __expf(a10);
  a11 = (a11 > 0.f) ? a11 + 1.f : __expf(a11);
  float cs0 = a00 + a10, cs1 = a01 + a11;

  if (g < 4) {
    *(float2*)&sbase[Q_OFF + (size_t)(cbase + l) * 8 + h0]      = make_float2(a00, a01);
    *(float2*)&sbase[Q_OFF + (size_t)(cbase + l + 32) * 8 + h0] = make_float2(a10, a11);
  } else {
    *(float2*)&kc[l][h0]      = make_float2(a00, a01);
    *(float2*)&kc[l + 32][h0] = make_float2(a10, a11);
  }
  __syncthreads();

  // ---- y[h, cols] += sum_r k[h,r] * x[r,cols]; wave rg owns rows rg*16..+15,
  //      each thread 4 columns ----
  const int rg = tid >> 6, c4 = (tid & 63) << 2;
  const int sy = c4 >> 3, hy = (c4 >> 2) & 1;
  float yr[HDIM][4];
  #pragma unroll
  for (int h = 0; h < HDIM; ++h) { yr[h][0] = 0.f; yr[h][1] = 0.f; yr[h][2] = 0.f; yr[h][3] = 0.f; }
  #pragma unroll 4
  for (int i = 0; i < 16; ++i) {
    int r = (rg << 4) + i;
    ushort4 xv = *(const ushort4*)(xb + r * 512 + ((sy ^ (r & 7)) << 4) + (hy << 3));
    float x0 = bf2f(xv.x), x1 = bf2f(xv.y), x2 = bf2f(xv.z), x3 = bf2f(xv.w);
    float4 k0 = *(const float4*)&kc[r][0];
    float4 k1 = *(const float4*)&kc[r][4];
    float kh[8] = {k0.x, k0.y, k0.z, k0.w, k1.x, k1.y, k1.z, k1.w};
    #pragma unroll
    for (int h = 0; h < HDIM; ++h) {
      yr[h][0] += kh[h] * x0; yr[h][1] += kh[h] * x1;
      yr[h][2] += kh[h] * x2; yr[h][3] += kh[h] * x3;
    }
  }
  __syncthreads();                 // xs reads done; overlay it
  float* ovl = (float*)xb;         // [4][8][256] = 32768 B
  #pragma unroll
  for (int h = 0; h < HDIM; ++h)
    *(float4*)&ovl[((rg << 3) + h) * 256 + c4] = make_float4(yr[h][0], yr[h][1], yr[h][2], yr[h][3]);
  __syncthreads();
  float* yp = sbase + YP_OFF + (size_t)sp * (HDIM * EDIM);
  #pragma unroll
  for (int h = 0; h < HDIM; ++h) {
    float v = ovl[h * 256 + tid] + ovl[(8 + h) * 256 + tid]
            + ovl[(16 + h) * 256 + tid] + ovl[(24 + h) * 256 + tid];
    yp[h * EDIM + tid] = v;
  }

  // ---- Qsum/Ksum partials: reduce over the 32-lane group ----
  #pragma unroll
  for (int off = 16; off >= 1; off >>= 1) {
    cs0 += __shfl_xor(cs0, off, 64);
    cs1 += __shfl_xor(cs1, off, 64);
  }
  if ((tid & 31) == 0) {
    if (g < 4) *(float2*)&sbase[QS_OFF + sp * HDIM + h0] = make_float2(cs0, cs1);
    else       *(float2*)&sbase[KS_OFF + sp * HDIM + h0] = make_float2(cs0, cs1);
  }
}

// ---- Phase 2: per pair: reduce partials -> ktv -> Msh. 380 blocks. ----
__global__ void __launch_bounds__(256, 2)
sla_phase2(const void* __restrict__ Wv, const void* __restrict__ bv,
           const void* __restrict__ Wo,
           const int* __restrict__ flags,
           float* __restrict__ scratch, long long sstride)
{
  const int fwv = flags[5], fbv = flags[6], fwo = flags[7];
  __shared__ __align__(16) float ysh[HDIM][EDIM];
  __shared__ __align__(16) float ktv[HDIM][DDIM];
  __shared__ float sQ[HDIM], sK[HDIM];
  const int tid = threadIdx.x;
  float* sbase = scratch + (size_t)blockIdx.x * (size_t)sstride;

  if (tid < 16) {
    int h = tid & 7;
    const float* ps = sbase + ((tid < 8) ? QS_OFF : KS_OFF);
    float s = 0.f;
    #pragma unroll
    for (int sp = 0; sp < NSPLIT; ++sp) s += ps[sp * HDIM + h];
    if (tid < 8) sQ[h] = 512.f / s;
    else         sK[h] = 1.f / s;
  }
  __syncthreads();

  {
    const float* yp = sbase + YP_OFF;
    #pragma unroll
    for (int h = 0; h < HDIM; ++h) {
      float y = 0.f;
      #pragma unroll
      for (int sp = 0; sp < NSPLIT; ++sp) y += yp[(sp * HDIM + h) * EDIM + tid];
      ysh[h][tid] = y * sK[h];
    }
  }
  __syncthreads();

  // ---- ktv[h,d] = ysh[h,:] . Wv[h*32+d,:] + bv ----
  {
    const int h = tid >> 5, d = tid & 31;
    const size_t wvrow = (size_t)(h * DDIM + d) * EDIM;
    float acc = 0.f;
    #pragma unroll 4
    for (int e = 0; e < EDIM; e += 8) {
      float4 wa = ld4(Wv, wvrow + e, fwv);
      float4 wb = ld4(Wv, wvrow + e + 4, fwv);
      float4 ya = *(const float4*)&ysh[h][e];
      float4 yb = *(const float4*)&ysh[h][e + 4];
      acc += wa.x * ya.x + wa.y * ya.y + wa.z * ya.z + wa.w * ya.w
           + wb.x * yb.x + wb.y * yb.y + wb.z * yb.z + wb.w * yb.w;
    }
    ktv[h][d] = acc + ld1(bv, h * DDIM + d, fbv);
  }
  __syncthreads();

  // ---- Msh[h][f] = (C/Qsum[h]) * ktv[h,:] . Wo[f, h*32..] ----
  {
    const int f = tid;
    const size_t worow = (size_t)f * EDIM;
    float* msh = sbase + MSH_OFF;
    #pragma unroll
    for (int h = 0; h < HDIM; ++h) {
      float m = 0.f;
      #pragma unroll
      for (int d = 0; d < DDIM; d += 8) {
        float4 wa = ld4(Wo, worow + h * DDIM + d, fwo);
        float4 wb = ld4(Wo, worow + h * DDIM + d + 4, fwo);
        float4 ka = *(const float4*)&ktv[h][d];
        float4 kb = *(const float4*)&ktv[h][d + 4];
        m += wa.x * ka.x + wa.y * ka.y + wa.z * ka.z + wa.w * ka.w
           + wb.x * kb.x + wb.y * kb.y + wb.z * kb.z + wb.w * kb.w;
      }
      msh[h * EDIM + f] = m * sQ[h];
    }
  }
}

// ---- Phase 3: rank-8 epilogue, streaming fp32 output.
//      shift=2: 4 blocks/pair (scratch in ws). shift=0: 1 block/pair
//      (scratch aliased into out region; stage to LDS, sync, then overwrite).
__global__ void __launch_bounds__(256, 2)
sla_phase3(const float* __restrict__ scratch, long long sstride,
           const void* __restrict__ bo, const int* __restrict__ flags,
           float* __restrict__ outg, int shift)
{
  const int fbo = flags[8];
  __shared__ __align__(16) float qsh[CDIM][HDIM];   // 16 KB (worst case)
  __shared__ __align__(16) float msh[HDIM][EDIM];   //  8 KB
  const int tid  = threadIdx.x;
  const int pair = blockIdx.x >> shift;
  const int seg  = blockIdx.x & ((1 << shift) - 1);
  const int rows = CDIM >> shift;
  const int c0   = seg * rows;
  const float* sbase = scratch + (size_t)pair * (size_t)sstride;

  for (int i = tid; i < rows * HDIM / 4; i += 256) {
    *(float4*)&qsh[i >> 1][(i & 1) * 4] =
        *(const float4*)&sbase[Q_OFF + (size_t)c0 * HDIM + (size_t)i * 4];
  }
  {
    const float* mp = sbase + MSH_OFF;
    for (int i = tid; i < HDIM * EDIM / 4; i += 256) {
      *(float4*)((float*)msh + (size_t)i * 4) = *(const float4*)&mp[(size_t)i * 4];
    }
  }
  __syncthreads();

  const int fq = tid & 63, cg = tid >> 6;
  const int f0 = fq * 4;
  float M[HDIM][4];
  #pragma unroll
  for (int h = 0; h < HDIM; ++h) {
    float4 mm = *(const float4*)&msh[h][f0];
    M[h][0] = mm.x; M[h][1] = mm.y; M[h][2] = mm.z; M[h][3] = mm.w;
  }
  const float b0 = ld1(bo, f0 + 0, fbo), b1 = ld1(bo, f0 + 1, fbo),
              b2 = ld1(bo, f0 + 2, fbo), b3 = ld1(bo, f0 + 3, fbo);
  float* outp = outg + (size_t)pair * OUT_STRIDE;
  const int rpw = rows >> 2;
  for (int i = 0; i < rpw; ++i) {
    int c = cg * rpw + i;
    float4 qa = *(const float4*)&qsh[c][0];
    float4 qb = *(const float4*)&qsh[c][4];
    float o0 = b0 + qa.x * M[0][0] + qa.y * M[1][0] + qa.z * M[2][0] + qa.w * M[3][0]
                  + qb.x * M[4][0] + qb.y * M[5][0] + qb.z * M[6][0] + qb.w * M[7][0];
    float o1 = b1 + qa.x * M[0][1] + qa.y * M[1][1] + qa.z * M[2][1] + qa.w * M[3][1]
                  + qb.x * M[4][1] + qb.y * M[5][1] + qb.z * M[6][1] + qb.w * M[7][1];
    float o2 = b2 + qa.x * M[0][2] + qa.y * M[1][2] + qa.z * M[2][2] + qa.w * M[3][2]
                  + qb.x * M[4][2] + qb.y * M[5][2] + qb.z * M[6][2] + qb.w * M[7][2];
    float o3 = b3 + qa.x * M[0][3] + qa.y * M[1][3] + qa.z * M[2][3] + qa.w * M[3][3]
                  + qb.x * M[4][3] + qb.y * M[5][3] + qb.z * M[6][3] + qb.w * M[7][3];
    *(float4*)(outp + (size_t)(c0 + c) * EDIM + f0) = make_float4(o0, o1, o2, o3);
  }
}

extern "C" void kernel_launch(void* const* d_in, const int* in_sizes, int n_in,
                              void* d_out, int out_size, void* d_ws, size_t ws_size,
                              hipStream_t stream) {
  (void)n_in; (void)out_size;
  int* flags = (int*)d_ws;

  // Scratch placement: workspace if big enough, else stash inside the output
  // buffer (phase3 then runs 1 block/pair, staging before overwrite).
  const size_t need = WS_SCR_OFF + (size_t)PAIRS * SCR_FLOATS * sizeof(float);
  float*    scratch;
  float*    cw;
  float*    cb;
  long long sstride;
  int       shift;
  if (ws_size >= need) {
    cw      = (float*)((char*)d_ws + WS_CW_OFF);
    cb      = (float*)((char*)d_ws + WS_CB_OFF);
    scratch = (float*)((char*)d_ws + WS_SCR_OFF);
    sstride = SCR_FLOATS;
    shift   = 2;            // 4 epilogue blocks per pair
  } else {
    scratch = (float*)d_out;
    sstride = OUT_STRIDE;
    shift   = 0;            // 1 epilogue block per pair
    // carve canonical weights from the tail pair's out region (dead by the
    // time phase3 overwrites it; disjoint from that pair's scratch)
    cw = (float*)d_out + (size_t)(PAIRS - 1) * OUT_STRIDE + 65536;
    cb = cw + 16 * EDIM;
  }

  hipLaunchKernelGGL(sniff_pack, dim3(1), dim3(256), 0, stream,
                     (const uint16_t*)d_in[0], (const uint16_t*)d_in[1],
                     (const uint16_t*)d_in[2], (const uint16_t*)d_in[3],
                     (const uint16_t*)d_in[4], (const uint16_t*)d_in[5],
                     (const uint16_t*)d_in[6], (const uint16_t*)d_in[7],
                     (const uint16_t*)d_in[8],
                     in_sizes[0], in_sizes[1], in_sizes[2], in_sizes[3], in_sizes[4],
                     in_sizes[5], in_sizes[6], in_sizes[7], in_sizes[8], flags,
                     cw, cb);

  hipLaunchKernelGGL(sla_phase1, dim3(PAIRS * NSPLIT), dim3(256), 0, stream,
                     d_in[0], (const float*)cw, (const float*)cb,
                     (const int*)flags, scratch, sstride);
  hipLaunchKernelGGL(sla_phase2, dim3(PAIRS), dim3(256), 0, stream,
                     d_in[5], d_in[6], d_in[7], (const int*)flags, scratch, sstride);
  hipLaunchKernelGGL(sla_phase3, dim3(PAIRS << shift), dim3(256), 0, stream,
                     scratch, sstride, d_in[8], (const int*)flags,
                     (float*)d_out, shift);
}